// Round 1
// baseline (12319.136 us; speedup 1.0000x reference)
//
#include <hip/hip_runtime.h>

#define B_ 64
#define S_ 1024
#define H_ 768
#define GB 4    // batch groups (16 rows each)
#define GC 24   // column groups (32 cols each)

typedef short s16x8 __attribute__((ext_vector_type(8)));
typedef float f32x4 __attribute__((ext_vector_type(4)));

__device__ __forceinline__ unsigned short f2b(float f) {
  unsigned u = __builtin_bit_cast(unsigned, f);
  u += 0x7FFFu + ((u >> 16) & 1u);
  return (unsigned short)(u >> 16);
}
__device__ __forceinline__ float b2f(unsigned short h) {
  unsigned u = ((unsigned)h) << 16;
  return __builtin_bit_cast(float, u);
}

__global__ void conv_f2b_kernel(const float* __restrict__ src,
                                unsigned short* __restrict__ dst, int n) {
  int i = (blockIdx.x * blockDim.x + threadIdx.x) * 4;
  if (i >= n) return;
  float4 v = *(const float4*)(src + i);
  unsigned long long p = (unsigned long long)f2b(v.x)
      | ((unsigned long long)f2b(v.y) << 16)
      | ((unsigned long long)f2b(v.z) << 32)
      | ((unsigned long long)f2b(v.w) << 48);
  *(unsigned long long*)(dst + i) = p;
}

__global__ void tail_kernel(const unsigned short* __restrict__ src,
                            float* __restrict__ dst, int n) {
  int i = blockIdx.x * blockDim.x + threadIdx.x;
  if (i < n) dst[i] = b2f(src[i]);
}

// C[r][n] = sum_k A[r][k] * W[n][k] + bias.  MODE0: A fp32 (x), bias1+bias2.
// MODE1: A bf16 (hseq, row-gathered: r=b*1024+s -> hseq[(s+1)*64+b]), bias1.
template <int MODE>
__global__ __launch_bounds__(256) void gemm_kernel(
    const void* __restrict__ Aptr, const unsigned short* __restrict__ Bw,
    float* __restrict__ C, const float* __restrict__ bias1,
    const float* __restrict__ bias2) {
  __shared__ unsigned short As[128 * 64];
  __shared__ unsigned short Bs[128 * 64];
  const int tid = threadIdx.x;
  const int l = tid & 63;
  const int w = tid >> 6;
  const int wm = w >> 1, wn = w & 1;
  const int r0 = blockIdx.x * 128;
  const int n0 = blockIdx.y * 128;
  const int row16 = l & 15;
  const int g4 = l >> 4;
  const int swz = (l & 7) << 3;

  const int srow = tid >> 1;
  const int shalf = (tid & 1) * 32;
  size_t a_off;
  if (MODE == 0) {
    a_off = (size_t)(r0 + srow) * 768;
  } else {
    int ar = r0 + srow;
    a_off = ((size_t)((ar & 1023) + 1) * 64 + (ar >> 10)) * 768;
  }
  const size_t b_off = (size_t)(n0 + srow) * 768;
  const int swrow = (srow & 7) << 3;

  f32x4 acc[4][4] = {};

  for (int k0 = 0; k0 < 768; k0 += 64) {
    if (MODE == 0) {
      const float* Af = (const float*)Aptr + a_off + k0 + shalf;
#pragma unroll
      for (int jj = 0; jj < 4; ++jj) {
        float4 v0 = *(const float4*)(Af + jj * 8);
        float4 v1 = *(const float4*)(Af + jj * 8 + 4);
        uint4 p;
        p.x = f2b(v0.x) | ((unsigned)f2b(v0.y) << 16);
        p.y = f2b(v0.z) | ((unsigned)f2b(v0.w) << 16);
        p.z = f2b(v1.x) | ((unsigned)f2b(v1.y) << 16);
        p.w = f2b(v1.z) | ((unsigned)f2b(v1.w) << 16);
        int c = (shalf + jj * 8) ^ swrow;
        *(uint4*)(As + srow * 64 + c) = p;
      }
    } else {
      const unsigned short* Ab = (const unsigned short*)Aptr + a_off + k0 + shalf;
#pragma unroll
      for (int jj = 0; jj < 4; ++jj) {
        uint4 p = *(const uint4*)(Ab + jj * 8);
        int c = (shalf + jj * 8) ^ swrow;
        *(uint4*)(As + srow * 64 + c) = p;
      }
    }
    {
      const unsigned short* Bb = Bw + b_off + k0 + shalf;
#pragma unroll
      for (int jj = 0; jj < 4; ++jj) {
        uint4 p = *(const uint4*)(Bb + jj * 8);
        int c = (shalf + jj * 8) ^ swrow;
        *(uint4*)(Bs + srow * 64 + c) = p;
      }
    }
    __syncthreads();
#pragma unroll
    for (int kb = 0; kb < 2; ++kb) {
      int ccol = (kb * 32 + g4 * 8) ^ swz;
      s16x8 af[4], bfr[4];
#pragma unroll
      for (int mi = 0; mi < 4; ++mi)
        af[mi] = __builtin_bit_cast(
            s16x8, *(const uint4*)(As + (wm * 64 + mi * 16 + row16) * 64 + ccol));
#pragma unroll
      for (int ni = 0; ni < 4; ++ni)
        bfr[ni] = __builtin_bit_cast(
            s16x8, *(const uint4*)(Bs + (wn * 64 + ni * 16 + row16) * 64 + ccol));
#pragma unroll
      for (int mi = 0; mi < 4; ++mi)
#pragma unroll
        for (int ni = 0; ni < 4; ++ni)
          acc[mi][ni] = __builtin_amdgcn_mfma_f32_16x16x32_bf16(
              af[mi], bfr[ni], acc[mi][ni], 0, 0, 0);
    }
    __syncthreads();
  }
#pragma unroll
  for (int ni = 0; ni < 4; ++ni) {
    int col = n0 + wn * 64 + ni * 16 + row16;
    float bv = bias1[col] + (MODE == 0 ? bias2[col] : 0.0f);
#pragma unroll
    for (int mi = 0; mi < 4; ++mi) {
      int rbase = r0 + wm * 64 + mi * 16 + g4 * 4;
#pragma unroll
      for (int i = 0; i < 4; ++i)
        C[(size_t)(rbase + i) * 768 + col] = acc[mi][ni][i] + bv;
    }
  }
}

// Persistent recurrence kernel: 96 blocks = 4 batch-groups x 24 col-groups,
// 128 threads (2 waves, each owns a 16-col n-tile).  W_hh slice lives in
// VGPRs as pre-packed MFMA A-fragments.  Computes G[n'][b] = W_slice . h^T.
__global__ __launch_bounds__(128) void scan_kernel(
    const float* __restrict__ W_hh, const float* __restrict__ xp,
    unsigned short* __restrict__ hseq, int* __restrict__ flags) {
  const int tid = threadIdx.x;
  const int l = tid & 63;
  const int w = tid >> 6;
  const int bg = blockIdx.x / GC;
  const int cg = blockIdx.x % GC;
  const int b0 = bg * 16;
  const int c0 = cg * 32;
  const int row16 = l & 15;
  const int g4 = l >> 4;

  // pack W_hh fragments: A[row=l&15][k = kb*32 + (l>>4)*8 + j]
  uint4 wfrag[24];
  {
    const float* wr = W_hh + (size_t)(c0 + w * 16 + row16) * 768;
#pragma unroll
    for (int kb = 0; kb < 24; ++kb) {
      int k0 = kb * 32 + g4 * 8;
      float4 v0 = *(const float4*)(wr + k0);
      float4 v1 = *(const float4*)(wr + k0 + 4);
      uint4 p;
      p.x = f2b(v0.x) | ((unsigned)f2b(v0.y) << 16);
      p.y = f2b(v0.z) | ((unsigned)f2b(v0.w) << 16);
      p.z = f2b(v1.x) | ((unsigned)f2b(v1.y) << 16);
      p.w = f2b(v1.z) | ((unsigned)f2b(v1.w) << 16);
      wfrag[kb] = p;
    }
  }

  const int fl = (l < 48) ? l : 0;
  const size_t hcol = c0 + w * 16 + g4 * 4;
  unsigned short* hout_base = hseq + (size_t)(b0 + row16) * 768 + hcol;
  const unsigned short* hin_row = hseq + (size_t)(b0 + row16) * 768;
  const float* xp_row = xp + (size_t)(b0 + row16) * 1024 * 768 + hcol;

  for (int t = 0; t < S_; ++t) {
    float4 xpv = *(const float4*)(xp_row + (size_t)t * 768);  // prefetch
    if (t > 0) {
      int* fp = flags + ((t - 1) * GB + bg) * 48 + fl;
      while (1) {
        int v = __hip_atomic_load(fp, __ATOMIC_RELAXED, __HIP_MEMORY_SCOPE_AGENT);
        if (__all((l >= 48) | (v != 0))) break;
        __builtin_amdgcn_s_sleep(1);
      }
      __builtin_amdgcn_fence(__ATOMIC_ACQUIRE, "agent");
    }
    const unsigned short* hin = hin_row + (size_t)t * (B_ * H_);
    uint4 hb[24];
#pragma unroll
    for (int kb = 0; kb < 24; ++kb)
      hb[kb] = *(const uint4*)(hin + kb * 32 + g4 * 8);
    f32x4 acc0 = {xpv.x, xpv.y, xpv.z, xpv.w};
    f32x4 acc1 = {0.f, 0.f, 0.f, 0.f};
#pragma unroll
    for (int kb = 0; kb < 24; kb += 2) {
      acc0 = __builtin_amdgcn_mfma_f32_16x16x32_bf16(
          __builtin_bit_cast(s16x8, wfrag[kb]),
          __builtin_bit_cast(s16x8, hb[kb]), acc0, 0, 0, 0);
      acc1 = __builtin_amdgcn_mfma_f32_16x16x32_bf16(
          __builtin_bit_cast(s16x8, wfrag[kb + 1]),
          __builtin_bit_cast(s16x8, hb[kb + 1]), acc1, 0, 0, 0);
    }
    f32x4 g = acc0 + acc1;
    float t0 = tanhf(g[0]), t1 = tanhf(g[1]), t2 = tanhf(g[2]), t3 = tanhf(g[3]);
    unsigned long long pk = (unsigned long long)f2b(t0)
        | ((unsigned long long)f2b(t1) << 16)
        | ((unsigned long long)f2b(t2) << 32)
        | ((unsigned long long)f2b(t3) << 48);
    *(unsigned long long*)(hout_base + (size_t)(t + 1) * (B_ * H_)) = pk;
    __builtin_amdgcn_fence(__ATOMIC_RELEASE, "agent");
    if (l == 0) {
      __hip_atomic_store(flags + (t * GB + bg) * 48 + cg * 2 + w, 1,
                         __ATOMIC_RELAXED, __HIP_MEMORY_SCOPE_AGENT);
    }
  }
}

extern "C" void kernel_launch(void* const* d_in, const int* in_sizes, int n_in,
                              void* d_out, int out_size, void* d_ws,
                              size_t ws_size, hipStream_t stream) {
  const float* hidden = (const float*)d_in[0];
  const float* x = (const float*)d_in[1];
  const float* W_ih = (const float*)d_in[2];
  const float* W_hh = (const float*)d_in[3];
  const float* b_ih = (const float*)d_in[4];
  const float* b_hh = (const float*)d_in[5];
  const float* W_fc = (const float*)d_in[6];
  const float* b_fc = (const float*)d_in[7];
  float* out = (float*)d_out;
  float* xp = out;  // xp [B*S][768] fp32 reuses the logits region (overwritten later)

  char* ws = (char*)d_ws;
  unsigned short* hseq = (unsigned short*)ws;  // [(S+1)][B][H] bf16
  size_t hseq_elems = (size_t)(S_ + 1) * B_ * H_;
  unsigned short* wih_b = hseq + hseq_elems;
  unsigned short* wfc_b = wih_b + 768 * 768;
  int* flags = (int*)(wfc_b + 768 * 768);  // [S][GB][48]

  hipMemsetAsync(flags, 0, (size_t)S_ * GB * 48 * sizeof(int), stream);
  conv_f2b_kernel<<<576, 256, 0, stream>>>(W_ih, wih_b, 768 * 768);
  conv_f2b_kernel<<<576, 256, 0, stream>>>(W_fc, wfc_b, 768 * 768);
  conv_f2b_kernel<<<48, 256, 0, stream>>>(hidden, hseq, B_ * H_);
  dim3 grid(512, 6);
  gemm_kernel<0><<<grid, 256, 0, stream>>>(x, wih_b, xp, b_ih, b_hh);
  scan_kernel<<<GB * GC, 128, 0, stream>>>(W_hh, xp, hseq, flags);
  gemm_kernel<1><<<grid, 256, 0, stream>>>(hseq, wfc_b, out, b_fc, nullptr);
  tail_kernel<<<192, 256, 0, stream>>>(hseq + (size_t)S_ * B_ * H_,
                                       out + (size_t)65536 * 768, B_ * H_);
}

// Round 2
// 6326.720 us; speedup vs baseline: 1.9472x; 1.9472x over previous
//
#include <hip/hip_runtime.h>

#define B_ 64
#define S_ 1024
#define H_ 768
#define GB 4    // batch groups (16 rows each)
#define GC 24   // column groups (32 cols each)

typedef short s16x8 __attribute__((ext_vector_type(8)));
typedef float f32x4 __attribute__((ext_vector_type(4)));

__device__ __forceinline__ unsigned short f2b(float f) {
  unsigned u = __builtin_bit_cast(unsigned, f);
  u += 0x7FFFu + ((u >> 16) & 1u);
  return (unsigned short)(u >> 16);
}
__device__ __forceinline__ float b2f(unsigned short h) {
  unsigned u = ((unsigned)h) << 16;
  return __builtin_bit_cast(float, u);
}

__global__ void conv_f2b_kernel(const float* __restrict__ src,
                                unsigned short* __restrict__ dst, int n) {
  int i = (blockIdx.x * blockDim.x + threadIdx.x) * 4;
  if (i >= n) return;
  float4 v = *(const float4*)(src + i);
  unsigned long long p = (unsigned long long)f2b(v.x)
      | ((unsigned long long)f2b(v.y) << 16)
      | ((unsigned long long)f2b(v.z) << 32)
      | ((unsigned long long)f2b(v.w) << 48);
  *(unsigned long long*)(dst + i) = p;
}

__global__ void tail_kernel(const unsigned short* __restrict__ src,
                            float* __restrict__ dst, int n) {
  int i = blockIdx.x * blockDim.x + threadIdx.x;
  if (i < n) dst[i] = b2f(src[i]);
}

// C[r][n] = sum_k A[r][k] * W[n][k] + bias.  MODE0: A fp32 (x), bias1+bias2.
// MODE1: A bf16 (hseq, row-gathered: r=b*1024+s -> hseq[(s+1)*64+b]), bias1.
template <int MODE>
__global__ __launch_bounds__(256) void gemm_kernel(
    const void* __restrict__ Aptr, const unsigned short* __restrict__ Bw,
    float* __restrict__ C, const float* __restrict__ bias1,
    const float* __restrict__ bias2) {
  __shared__ unsigned short As[128 * 64];
  __shared__ unsigned short Bs[128 * 64];
  const int tid = threadIdx.x;
  const int l = tid & 63;
  const int w = tid >> 6;
  const int wm = w >> 1, wn = w & 1;
  const int r0 = blockIdx.x * 128;
  const int n0 = blockIdx.y * 128;
  const int row16 = l & 15;
  const int g4 = l >> 4;
  const int swz = (l & 7) << 3;

  const int srow = tid >> 1;
  const int shalf = (tid & 1) * 32;
  size_t a_off;
  if (MODE == 0) {
    a_off = (size_t)(r0 + srow) * 768;
  } else {
    int ar = r0 + srow;
    a_off = ((size_t)((ar & 1023) + 1) * 64 + (ar >> 10)) * 768;
  }
  const size_t b_off = (size_t)(n0 + srow) * 768;
  const int swrow = (srow & 7) << 3;

  f32x4 acc[4][4] = {};

  for (int k0 = 0; k0 < 768; k0 += 64) {
    if (MODE == 0) {
      const float* Af = (const float*)Aptr + a_off + k0 + shalf;
#pragma unroll
      for (int jj = 0; jj < 4; ++jj) {
        float4 v0 = *(const float4*)(Af + jj * 8);
        float4 v1 = *(const float4*)(Af + jj * 8 + 4);
        uint4 p;
        p.x = f2b(v0.x) | ((unsigned)f2b(v0.y) << 16);
        p.y = f2b(v0.z) | ((unsigned)f2b(v0.w) << 16);
        p.z = f2b(v1.x) | ((unsigned)f2b(v1.y) << 16);
        p.w = f2b(v1.z) | ((unsigned)f2b(v1.w) << 16);
        int c = (shalf + jj * 8) ^ swrow;
        *(uint4*)(As + srow * 64 + c) = p;
      }
    } else {
      const unsigned short* Ab = (const unsigned short*)Aptr + a_off + k0 + shalf;
#pragma unroll
      for (int jj = 0; jj < 4; ++jj) {
        uint4 p = *(const uint4*)(Ab + jj * 8);
        int c = (shalf + jj * 8) ^ swrow;
        *(uint4*)(As + srow * 64 + c) = p;
      }
    }
    {
      const unsigned short* Bb = Bw + b_off + k0 + shalf;
#pragma unroll
      for (int jj = 0; jj < 4; ++jj) {
        uint4 p = *(const uint4*)(Bb + jj * 8);
        int c = (shalf + jj * 8) ^ swrow;
        *(uint4*)(Bs + srow * 64 + c) = p;
      }
    }
    __syncthreads();
#pragma unroll
    for (int kb = 0; kb < 2; ++kb) {
      int ccol = (kb * 32 + g4 * 8) ^ swz;
      s16x8 af[4], bfr[4];
#pragma unroll
      for (int mi = 0; mi < 4; ++mi)
        af[mi] = __builtin_bit_cast(
            s16x8, *(const uint4*)(As + (wm * 64 + mi * 16 + row16) * 64 + ccol));
#pragma unroll
      for (int ni = 0; ni < 4; ++ni)
        bfr[ni] = __builtin_bit_cast(
            s16x8, *(const uint4*)(Bs + (wn * 64 + ni * 16 + row16) * 64 + ccol));
#pragma unroll
      for (int mi = 0; mi < 4; ++mi)
#pragma unroll
        for (int ni = 0; ni < 4; ++ni)
          acc[mi][ni] = __builtin_amdgcn_mfma_f32_16x16x32_bf16(
              af[mi], bfr[ni], acc[mi][ni], 0, 0, 0);
    }
    __syncthreads();
  }
#pragma unroll
  for (int ni = 0; ni < 4; ++ni) {
    int col = n0 + wn * 64 + ni * 16 + row16;
    float bv = bias1[col] + (MODE == 0 ? bias2[col] : 0.0f);
#pragma unroll
    for (int mi = 0; mi < 4; ++mi) {
      int rbase = r0 + wm * 64 + mi * 16 + g4 * 4;
#pragma unroll
      for (int i = 0; i < 4; ++i)
        C[(size_t)(rbase + i) * 768 + col] = acc[mi][ni][i] + bv;
    }
  }
}

// Persistent recurrence kernel: 96 blocks = 4 batch-groups x 24 col-groups,
// 128 threads (2 waves, each owns a 16-col n-tile).  W_hh slice lives in
// VGPRs as pre-packed MFMA A-fragments.
//
// Cross-block h exchange: NO fences (agent fences on gfx950 = full L2
// wbl2/inv per step = 11.6 us/step measured in R0).  Instead all shared
// traffic (h, flags) uses per-access agent scope (sc1 -> served at the
// coherent Infinity Cache, bypassing the non-coherent per-XCD L2s):
//   producer: h store (sc1) -> s_waitcnt vmcnt(0) -> flag store (sc1)
//   consumer: poll flag (sc1) -> h loads (sc1) -> vmcnt(0)+sched_barrier
__global__ __launch_bounds__(128) void scan_kernel(
    const float* __restrict__ W_hh, const float* __restrict__ xp,
    unsigned short* __restrict__ hseq, int* __restrict__ flags) {
  const int tid = threadIdx.x;
  const int l = tid & 63;
  const int w = tid >> 6;
  const int bg = blockIdx.x / GC;
  const int cg = blockIdx.x % GC;
  const int b0 = bg * 16;
  const int c0 = cg * 32;
  const int row16 = l & 15;
  const int g4 = l >> 4;

  // pack W_hh fragments: A[row=l&15][k = kb*32 + (l>>4)*8 + j]
  uint4 wfrag[24];
  {
    const float* wr = W_hh + (size_t)(c0 + w * 16 + row16) * 768;
#pragma unroll
    for (int kb = 0; kb < 24; ++kb) {
      int k0 = kb * 32 + g4 * 8;
      float4 v0 = *(const float4*)(wr + k0);
      float4 v1 = *(const float4*)(wr + k0 + 4);
      uint4 p;
      p.x = f2b(v0.x) | ((unsigned)f2b(v0.y) << 16);
      p.y = f2b(v0.z) | ((unsigned)f2b(v0.w) << 16);
      p.z = f2b(v1.x) | ((unsigned)f2b(v1.y) << 16);
      p.w = f2b(v1.z) | ((unsigned)f2b(v1.w) << 16);
      wfrag[kb] = p;
    }
  }

  const int fl = (l < 48) ? l : 0;
  const size_t hcol = c0 + w * 16 + g4 * 4;
  unsigned short* hout_base = hseq + (size_t)(b0 + row16) * 768 + hcol;
  const unsigned short* hin_row = hseq + (size_t)(b0 + row16) * 768;
  const float* xp_row = xp + (size_t)(b0 + row16) * 1024 * 768 + hcol;

  for (int t = 0; t < S_; ++t) {
    float4 xpv = *(const float4*)(xp_row + (size_t)t * 768);  // cached prefetch
    if (t > 0) {
      const int* fp = flags + ((t - 1) * GB + bg) * 48 + fl;
      while (1) {
        int v = __hip_atomic_load(fp, __ATOMIC_RELAXED, __HIP_MEMORY_SCOPE_AGENT);
        if (__all((l >= 48) | (v != 0))) break;
      }
    }
    const unsigned short* hin = hin_row + (size_t)t * (B_ * H_);
    uint4 hb[24];
#pragma unroll
    for (int kb = 0; kb < 24; ++kb) {
      asm volatile("global_load_dwordx4 %0, %1, off sc1"
                   : "=&v"(hb[kb])
                   : "v"(hin + kb * 32 + g4 * 8));
    }
    asm volatile("s_waitcnt vmcnt(0)" ::: "memory");
    __builtin_amdgcn_sched_barrier(0);

    f32x4 acc0 = {xpv.x, xpv.y, xpv.z, xpv.w};
    f32x4 acc1 = {0.f, 0.f, 0.f, 0.f};
#pragma unroll
    for (int kb = 0; kb < 24; kb += 2) {
      acc0 = __builtin_amdgcn_mfma_f32_16x16x32_bf16(
          __builtin_bit_cast(s16x8, wfrag[kb]),
          __builtin_bit_cast(s16x8, hb[kb]), acc0, 0, 0, 0);
      acc1 = __builtin_amdgcn_mfma_f32_16x16x32_bf16(
          __builtin_bit_cast(s16x8, wfrag[kb + 1]),
          __builtin_bit_cast(s16x8, hb[kb + 1]), acc1, 0, 0, 0);
    }
    f32x4 g = acc0 + acc1;
    float t0 = tanhf(g[0]), t1 = tanhf(g[1]), t2 = tanhf(g[2]), t3 = tanhf(g[3]);
    unsigned long long pk = (unsigned long long)f2b(t0)
        | ((unsigned long long)f2b(t1) << 16)
        | ((unsigned long long)f2b(t2) << 32)
        | ((unsigned long long)f2b(t3) << 48);
    __hip_atomic_store(
        (unsigned long long*)(hout_base + (size_t)(t + 1) * (B_ * H_)), pk,
        __ATOMIC_RELAXED, __HIP_MEMORY_SCOPE_AGENT);
    asm volatile("s_waitcnt vmcnt(0)" ::: "memory");
    if (l == 0) {
      __hip_atomic_store(flags + (t * GB + bg) * 48 + cg * 2 + w, 1,
                         __ATOMIC_RELAXED, __HIP_MEMORY_SCOPE_AGENT);
    }
  }
}

extern "C" void kernel_launch(void* const* d_in, const int* in_sizes, int n_in,
                              void* d_out, int out_size, void* d_ws,
                              size_t ws_size, hipStream_t stream) {
  const float* hidden = (const float*)d_in[0];
  const float* x = (const float*)d_in[1];
  const float* W_ih = (const float*)d_in[2];
  const float* W_hh = (const float*)d_in[3];
  const float* b_ih = (const float*)d_in[4];
  const float* b_hh = (const float*)d_in[5];
  const float* W_fc = (const float*)d_in[6];
  const float* b_fc = (const float*)d_in[7];
  float* out = (float*)d_out;
  float* xp = out;  // xp [B*S][768] fp32 reuses the logits region (overwritten later)

  char* ws = (char*)d_ws;
  unsigned short* hseq = (unsigned short*)ws;  // [(S+1)][B][H] bf16
  size_t hseq_elems = (size_t)(S_ + 1) * B_ * H_;
  unsigned short* wih_b = hseq + hseq_elems;
  unsigned short* wfc_b = wih_b + 768 * 768;
  int* flags = (int*)(wfc_b + 768 * 768);  // [S][GB][48]

  hipMemsetAsync(flags, 0, (size_t)S_ * GB * 48 * sizeof(int), stream);
  conv_f2b_kernel<<<576, 256, 0, stream>>>(W_ih, wih_b, 768 * 768);
  conv_f2b_kernel<<<576, 256, 0, stream>>>(W_fc, wfc_b, 768 * 768);
  conv_f2b_kernel<<<48, 256, 0, stream>>>(hidden, hseq, B_ * H_);
  dim3 grid(512, 6);
  gemm_kernel<0><<<grid, 256, 0, stream>>>(x, wih_b, xp, b_ih, b_hh);
  scan_kernel<<<GB * GC, 128, 0, stream>>>(W_hh, xp, hseq, flags);
  gemm_kernel<1><<<grid, 256, 0, stream>>>(hseq, wfc_b, out, b_fc, nullptr);
  tail_kernel<<<192, 256, 0, stream>>>(hseq + (size_t)S_ * B_ * H_,
                                       out + (size_t)65536 * 768, B_ * H_);
}

// Round 3
// 5004.968 us; speedup vs baseline: 2.4614x; 1.2641x over previous
//
#include <hip/hip_runtime.h>

#define B_ 64
#define S_ 1024
#define H_ 768
#define GB 4    // batch groups (16 rows each)
#define GC 24   // column groups (32 cols each)

typedef short s16x8 __attribute__((ext_vector_type(8)));
typedef float f32x4 __attribute__((ext_vector_type(4)));

__device__ __forceinline__ unsigned short f2b(float f) {
  unsigned u = __builtin_bit_cast(unsigned, f);
  u += 0x7FFFu + ((u >> 16) & 1u);
  return (unsigned short)(u >> 16);
}
__device__ __forceinline__ float b2f(unsigned short h) {
  unsigned u = ((unsigned)h) << 16;
  return __builtin_bit_cast(float, u);
}

// tanh(x) = 1 - 2/(1+e^{2x}); exact at +-inf, ~1e-7 rel err, no branches.
__device__ __forceinline__ float fast_tanh(float x) {
  float e = __builtin_amdgcn_exp2f(x * 2.8853900817779268f);  // e^{2x}
  return 1.0f - 2.0f * __builtin_amdgcn_rcpf(1.0f + e);
}

__global__ void conv_f2b_kernel(const float* __restrict__ src,
                                unsigned short* __restrict__ dst, int n) {
  int i = (blockIdx.x * blockDim.x + threadIdx.x) * 4;
  if (i >= n) return;
  float4 v = *(const float4*)(src + i);
  unsigned long long p = (unsigned long long)f2b(v.x)
      | ((unsigned long long)f2b(v.y) << 16)
      | ((unsigned long long)f2b(v.z) << 32)
      | ((unsigned long long)f2b(v.w) << 48);
  *(unsigned long long*)(dst + i) = p;
}

__global__ void tail_kernel(const unsigned short* __restrict__ src,
                            float* __restrict__ dst, int n) {
  int i = blockIdx.x * blockDim.x + threadIdx.x;
  if (i < n) dst[i] = b2f(src[i]);
}

// C[r][n] = sum_k A[r][k] * W[n][k] + bias.  MODE0: A fp32 (x), bias1+bias2.
// MODE1: A bf16 (hseq, row-gathered: r=b*1024+s -> hseq[(s+1)*64+b]), bias1.
template <int MODE>
__global__ __launch_bounds__(256) void gemm_kernel(
    const void* __restrict__ Aptr, const unsigned short* __restrict__ Bw,
    float* __restrict__ C, const float* __restrict__ bias1,
    const float* __restrict__ bias2) {
  __shared__ unsigned short As[128 * 64];
  __shared__ unsigned short Bs[128 * 64];
  const int tid = threadIdx.x;
  const int l = tid & 63;
  const int w = tid >> 6;
  const int wm = w >> 1, wn = w & 1;
  const int r0 = blockIdx.x * 128;
  const int n0 = blockIdx.y * 128;
  const int row16 = l & 15;
  const int g4 = l >> 4;
  const int swz = (l & 7) << 3;

  const int srow = tid >> 1;
  const int shalf = (tid & 1) * 32;
  size_t a_off;
  if (MODE == 0) {
    a_off = (size_t)(r0 + srow) * 768;
  } else {
    int ar = r0 + srow;
    a_off = ((size_t)((ar & 1023) + 1) * 64 + (ar >> 10)) * 768;
  }
  const size_t b_off = (size_t)(n0 + srow) * 768;
  const int swrow = (srow & 7) << 3;

  f32x4 acc[4][4] = {};

  for (int k0 = 0; k0 < 768; k0 += 64) {
    if (MODE == 0) {
      const float* Af = (const float*)Aptr + a_off + k0 + shalf;
#pragma unroll
      for (int jj = 0; jj < 4; ++jj) {
        float4 v0 = *(const float4*)(Af + jj * 8);
        float4 v1 = *(const float4*)(Af + jj * 8 + 4);
        uint4 p;
        p.x = f2b(v0.x) | ((unsigned)f2b(v0.y) << 16);
        p.y = f2b(v0.z) | ((unsigned)f2b(v0.w) << 16);
        p.z = f2b(v1.x) | ((unsigned)f2b(v1.y) << 16);
        p.w = f2b(v1.z) | ((unsigned)f2b(v1.w) << 16);
        int c = (shalf + jj * 8) ^ swrow;
        *(uint4*)(As + srow * 64 + c) = p;
      }
    } else {
      const unsigned short* Ab = (const unsigned short*)Aptr + a_off + k0 + shalf;
#pragma unroll
      for (int jj = 0; jj < 4; ++jj) {
        uint4 p = *(const uint4*)(Ab + jj * 8);
        int c = (shalf + jj * 8) ^ swrow;
        *(uint4*)(As + srow * 64 + c) = p;
      }
    }
    {
      const unsigned short* Bb = Bw + b_off + k0 + shalf;
#pragma unroll
      for (int jj = 0; jj < 4; ++jj) {
        uint4 p = *(const uint4*)(Bb + jj * 8);
        int c = (shalf + jj * 8) ^ swrow;
        *(uint4*)(Bs + srow * 64 + c) = p;
      }
    }
    __syncthreads();
#pragma unroll
    for (int kb = 0; kb < 2; ++kb) {
      int ccol = (kb * 32 + g4 * 8) ^ swz;
      s16x8 af[4], bfr[4];
#pragma unroll
      for (int mi = 0; mi < 4; ++mi)
        af[mi] = __builtin_bit_cast(
            s16x8, *(const uint4*)(As + (wm * 64 + mi * 16 + row16) * 64 + ccol));
#pragma unroll
      for (int ni = 0; ni < 4; ++ni)
        bfr[ni] = __builtin_bit_cast(
            s16x8, *(const uint4*)(Bs + (wn * 64 + ni * 16 + row16) * 64 + ccol));
#pragma unroll
      for (int mi = 0; mi < 4; ++mi)
#pragma unroll
        for (int ni = 0; ni < 4; ++ni)
          acc[mi][ni] = __builtin_amdgcn_mfma_f32_16x16x32_bf16(
              af[mi], bfr[ni], acc[mi][ni], 0, 0, 0);
    }
    __syncthreads();
  }
#pragma unroll
  for (int ni = 0; ni < 4; ++ni) {
    int col = n0 + wn * 64 + ni * 16 + row16;
    float bv = bias1[col] + (MODE == 0 ? bias2[col] : 0.0f);
#pragma unroll
    for (int mi = 0; mi < 4; ++mi) {
      int rbase = r0 + wm * 64 + mi * 16 + g4 * 4;
#pragma unroll
      for (int i = 0; i < 4; ++i)
        C[(size_t)(rbase + i) * 768 + col] = acc[mi][ni][i] + bv;
    }
  }
}

// Persistent recurrence kernel: 96 blocks = 4 batch-groups x 24 col-groups,
// 128 threads (2 waves, each owns a 16-col n-tile).  W_hh slice in VGPRs.
//
// Sync protocol (R2): NO flags, NO fences, NO store-ack.  The h data itself
// is the readiness signal: hseq[t>=1] is zeroed at launch; producers store
// 8B packed bf16 words (atomic, sc1 -> write-through to coherent IF) with a
// pk==0 -> pk=1 guard; consumers poll their own 16B chunks with sc1 loads in
// a done-bitmask loop (both 8B halves nonzero => chunk complete).  On poll
// success the data is already in registers: chain ~= 1.5 IF round trips.
__global__ __launch_bounds__(128) void scan_kernel(
    const float* __restrict__ W_hh, const float* __restrict__ xp,
    unsigned short* __restrict__ hseq) {
  const int tid = threadIdx.x;
  const int l = tid & 63;
  const int w = tid >> 6;
  const int bg = blockIdx.x / GC;
  const int cg = blockIdx.x % GC;
  const int b0 = bg * 16;
  const int c0 = cg * 32;
  const int row16 = l & 15;
  const int g4 = l >> 4;

  // pack W_hh fragments: A[row=l&15][k = kb*32 + (l>>4)*8 + j]
  uint4 wfrag[24];
  {
    const float* wr = W_hh + (size_t)(c0 + w * 16 + row16) * 768;
#pragma unroll
    for (int kb = 0; kb < 24; ++kb) {
      int k0 = kb * 32 + g4 * 8;
      float4 v0 = *(const float4*)(wr + k0);
      float4 v1 = *(const float4*)(wr + k0 + 4);
      uint4 p;
      p.x = f2b(v0.x) | ((unsigned)f2b(v0.y) << 16);
      p.y = f2b(v0.z) | ((unsigned)f2b(v0.w) << 16);
      p.z = f2b(v1.x) | ((unsigned)f2b(v1.y) << 16);
      p.w = f2b(v1.z) | ((unsigned)f2b(v1.w) << 16);
      wfrag[kb] = p;
    }
  }

  const size_t hcol = c0 + w * 16 + g4 * 4;
  unsigned short* hout_base = hseq + (size_t)(b0 + row16) * 768 + hcol;
  const unsigned short* hin_row = hseq + (size_t)(b0 + row16) * 768;
  const float* xp_row = xp + (size_t)(b0 + row16) * 1024 * 768 + hcol;

  for (int t = 0; t < S_; ++t) {
    float4 xpv = *(const float4*)(xp_row + (size_t)t * 768);  // off critical path
    const unsigned short* hin = hin_row + (size_t)t * (B_ * H_);
    uint4 hb[24];
    if (t == 0) {
      // h0 (= zeros) pre-written by conv kernel; kernel ordering guarantees
      // visibility; legitimately zero so no poll.
#pragma unroll
      for (int kb = 0; kb < 24; ++kb)
        asm volatile("global_load_dwordx4 %0, %1, off sc1"
                     : "=&v"(hb[kb])
                     : "v"(hin + kb * 32 + g4 * 8));
      asm volatile("s_waitcnt vmcnt(0)" ::: "memory");
    } else {
      unsigned done = 0;
      while (true) {
#pragma unroll
        for (int kb = 0; kb < 24; ++kb)
          if (!(done & (1u << kb)))
            asm volatile("global_load_dwordx4 %0, %1, off sc1"
                         : "=&v"(hb[kb])
                         : "v"(hin + kb * 32 + g4 * 8));
        asm volatile("s_waitcnt vmcnt(0)" ::: "memory");
        __builtin_amdgcn_sched_barrier(0);  // keep checks after the waitcnt
#pragma unroll
        for (int kb = 0; kb < 24; ++kb)
          if (!(done & (1u << kb)) && (hb[kb].x | hb[kb].y) != 0 &&
              (hb[kb].z | hb[kb].w) != 0)
            done |= 1u << kb;
        if (__all(done == 0xFFFFFFu)) break;
      }
    }
    __builtin_amdgcn_sched_barrier(0);

    f32x4 acc0 = {xpv.x, xpv.y, xpv.z, xpv.w};
    f32x4 acc1 = {0.f, 0.f, 0.f, 0.f};
    f32x4 acc2 = {0.f, 0.f, 0.f, 0.f};
    f32x4 acc3 = {0.f, 0.f, 0.f, 0.f};
#pragma unroll
    for (int kb = 0; kb < 24; kb += 4) {
      acc0 = __builtin_amdgcn_mfma_f32_16x16x32_bf16(
          __builtin_bit_cast(s16x8, wfrag[kb]),
          __builtin_bit_cast(s16x8, hb[kb]), acc0, 0, 0, 0);
      acc1 = __builtin_amdgcn_mfma_f32_16x16x32_bf16(
          __builtin_bit_cast(s16x8, wfrag[kb + 1]),
          __builtin_bit_cast(s16x8, hb[kb + 1]), acc1, 0, 0, 0);
      acc2 = __builtin_amdgcn_mfma_f32_16x16x32_bf16(
          __builtin_bit_cast(s16x8, wfrag[kb + 2]),
          __builtin_bit_cast(s16x8, hb[kb + 2]), acc2, 0, 0, 0);
      acc3 = __builtin_amdgcn_mfma_f32_16x16x32_bf16(
          __builtin_bit_cast(s16x8, wfrag[kb + 3]),
          __builtin_bit_cast(s16x8, hb[kb + 3]), acc3, 0, 0, 0);
    }
    f32x4 g = (acc0 + acc1) + (acc2 + acc3);
    float t0 = fast_tanh(g[0]), t1 = fast_tanh(g[1]);
    float t2 = fast_tanh(g[2]), t3 = fast_tanh(g[3]);
    unsigned long long pk = (unsigned long long)f2b(t0)
        | ((unsigned long long)f2b(t1) << 16)
        | ((unsigned long long)f2b(t2) << 32)
        | ((unsigned long long)f2b(t3) << 48);
    if (pk == 0) pk = 1;  // readiness sentinel: never store an all-zero word
    __hip_atomic_store(
        (unsigned long long*)(hout_base + (size_t)(t + 1) * (B_ * H_)), pk,
        __ATOMIC_RELAXED, __HIP_MEMORY_SCOPE_AGENT);
    // no vmcnt, no flag: the store drains while we poll for step t+1
  }
}

extern "C" void kernel_launch(void* const* d_in, const int* in_sizes, int n_in,
                              void* d_out, int out_size, void* d_ws,
                              size_t ws_size, hipStream_t stream) {
  const float* hidden = (const float*)d_in[0];
  const float* x = (const float*)d_in[1];
  const float* W_ih = (const float*)d_in[2];
  const float* W_hh = (const float*)d_in[3];
  const float* b_ih = (const float*)d_in[4];
  const float* b_hh = (const float*)d_in[5];
  const float* W_fc = (const float*)d_in[6];
  const float* b_fc = (const float*)d_in[7];
  float* out = (float*)d_out;
  float* xp = out;  // xp [B*S][768] fp32 reuses the logits region (overwritten later)

  char* ws = (char*)d_ws;
  unsigned short* hseq = (unsigned short*)ws;  // [(S+1)][B][H] bf16
  size_t hseq_elems = (size_t)(S_ + 1) * B_ * H_;
  unsigned short* wih_b = hseq + hseq_elems;
  unsigned short* wfc_b = wih_b + 768 * 768;

  // zero h[1..S]: required every launch (data-as-flag poll; ws not re-poisoned
  // between replays)
  hipMemsetAsync(hseq + (size_t)B_ * H_, 0, (size_t)S_ * B_ * H_ * 2, stream);
  conv_f2b_kernel<<<576, 256, 0, stream>>>(W_ih, wih_b, 768 * 768);
  conv_f2b_kernel<<<576, 256, 0, stream>>>(W_fc, wfc_b, 768 * 768);
  conv_f2b_kernel<<<48, 256, 0, stream>>>(hidden, hseq, B_ * H_);
  dim3 grid(512, 6);
  gemm_kernel<0><<<grid, 256, 0, stream>>>(x, wih_b, xp, b_ih, b_hh);
  scan_kernel<<<GB * GC, 128, 0, stream>>>(W_hh, xp, hseq);
  gemm_kernel<1><<<grid, 256, 0, stream>>>(hseq, wfc_b, out, b_fc, nullptr);
  tail_kernel<<<192, 256, 0, stream>>>(hseq + (size_t)S_ * B_ * H_,
                                       out + (size_t)65536 * 768, B_ * H_);
}

// Round 5
// 4896.696 us; speedup vs baseline: 2.5158x; 1.0221x over previous
//
#include <hip/hip_runtime.h>

#define B_ 64
#define S_ 1024
#define H_ 768
#define GB 4    // batch groups (16 rows each)
#define CB 6    // col-blocks per group (128 cols each)

typedef short s16x8 __attribute__((ext_vector_type(8)));
typedef float f32x4 __attribute__((ext_vector_type(4)));

__device__ __forceinline__ unsigned short f2b(float f) {
  unsigned u = __builtin_bit_cast(unsigned, f);
  u += 0x7FFFu + ((u >> 16) & 1u);
  return (unsigned short)(u >> 16);
}
__device__ __forceinline__ float b2f(unsigned short h) {
  unsigned u = ((unsigned)h) << 16;
  return __builtin_bit_cast(float, u);
}

// tanh(x) = 1 - 2/(1+e^{2x}); exact at +-inf, ~1e-7 rel err, no branches.
__device__ __forceinline__ float fast_tanh(float x) {
  float e = __builtin_amdgcn_exp2f(x * 2.8853900817779268f);  // e^{2x}
  return 1.0f - 2.0f * __builtin_amdgcn_rcpf(1.0f + e);
}

__global__ void conv_f2b_kernel(const float* __restrict__ src,
                                unsigned short* __restrict__ dst, int n) {
  int i = (blockIdx.x * blockDim.x + threadIdx.x) * 4;
  if (i >= n) return;
  float4 v = *(const float4*)(src + i);
  unsigned long long p = (unsigned long long)f2b(v.x)
      | ((unsigned long long)f2b(v.y) << 16)
      | ((unsigned long long)f2b(v.z) << 32)
      | ((unsigned long long)f2b(v.w) << 48);
  *(unsigned long long*)(dst + i) = p;
}

__global__ void tail_kernel(const unsigned short* __restrict__ src,
                            float* __restrict__ dst, int n) {
  int i = blockIdx.x * blockDim.x + threadIdx.x;
  if (i < n) dst[i] = b2f(src[i]);
}

// C[r][n] = sum_k A[r][k] * W[n][k] + bias.  MODE0: A fp32 (x), bias1+bias2.
// MODE1: A bf16 (hseq, row-gathered: r=b*1024+s -> hseq[(s+1)*64+b]), bias1.
template <int MODE>
__global__ __launch_bounds__(256) void gemm_kernel(
    const void* __restrict__ Aptr, const unsigned short* __restrict__ Bw,
    float* __restrict__ C, const float* __restrict__ bias1,
    const float* __restrict__ bias2) {
  __shared__ unsigned short As[128 * 64];
  __shared__ unsigned short Bs[128 * 64];
  const int tid = threadIdx.x;
  const int l = tid & 63;
  const int w = tid >> 6;
  const int wm = w >> 1, wn = w & 1;
  const int r0 = blockIdx.x * 128;
  const int n0 = blockIdx.y * 128;
  const int row16 = l & 15;
  const int g4 = l >> 4;
  const int swz = (l & 7) << 3;

  const int srow = tid >> 1;
  const int shalf = (tid & 1) * 32;
  size_t a_off;
  if (MODE == 0) {
    a_off = (size_t)(r0 + srow) * 768;
  } else {
    int ar = r0 + srow;
    a_off = ((size_t)((ar & 1023) + 1) * 64 + (ar >> 10)) * 768;
  }
  const size_t b_off = (size_t)(n0 + srow) * 768;
  const int swrow = (srow & 7) << 3;

  f32x4 acc[4][4] = {};

  for (int k0 = 0; k0 < 768; k0 += 64) {
    if (MODE == 0) {
      const float* Af = (const float*)Aptr + a_off + k0 + shalf;
#pragma unroll
      for (int jj = 0; jj < 4; ++jj) {
        float4 v0 = *(const float4*)(Af + jj * 8);
        float4 v1 = *(const float4*)(Af + jj * 8 + 4);
        uint4 p;
        p.x = f2b(v0.x) | ((unsigned)f2b(v0.y) << 16);
        p.y = f2b(v0.z) | ((unsigned)f2b(v0.w) << 16);
        p.z = f2b(v1.x) | ((unsigned)f2b(v1.y) << 16);
        p.w = f2b(v1.z) | ((unsigned)f2b(v1.w) << 16);
        int c = (shalf + jj * 8) ^ swrow;
        *(uint4*)(As + srow * 64 + c) = p;
      }
    } else {
      const unsigned short* Ab = (const unsigned short*)Aptr + a_off + k0 + shalf;
#pragma unroll
      for (int jj = 0; jj < 4; ++jj) {
        uint4 p = *(const uint4*)(Ab + jj * 8);
        int c = (shalf + jj * 8) ^ swrow;
        *(uint4*)(As + srow * 64 + c) = p;
      }
    }
    {
      const unsigned short* Bb = Bw + b_off + k0 + shalf;
#pragma unroll
      for (int jj = 0; jj < 4; ++jj) {
        uint4 p = *(const uint4*)(Bb + jj * 8);
        int c = (shalf + jj * 8) ^ swrow;
        *(uint4*)(Bs + srow * 64 + c) = p;
      }
    }
    __syncthreads();
#pragma unroll
    for (int kb = 0; kb < 2; ++kb) {
      int ccol = (kb * 32 + g4 * 8) ^ swz;
      s16x8 af[4], bfr[4];
#pragma unroll
      for (int mi = 0; mi < 4; ++mi)
        af[mi] = __builtin_bit_cast(
            s16x8, *(const uint4*)(As + (wm * 64 + mi * 16 + row16) * 64 + ccol));
#pragma unroll
      for (int ni = 0; ni < 4; ++ni)
        bfr[ni] = __builtin_bit_cast(
            s16x8, *(const uint4*)(Bs + (wn * 64 + ni * 16 + row16) * 64 + ccol));
#pragma unroll
      for (int mi = 0; mi < 4; ++mi)
#pragma unroll
        for (int ni = 0; ni < 4; ++ni)
          acc[mi][ni] = __builtin_amdgcn_mfma_f32_16x16x32_bf16(
              af[mi], bfr[ni], acc[mi][ni], 0, 0, 0);
    }
    __syncthreads();
  }
#pragma unroll
  for (int ni = 0; ni < 4; ++ni) {
    int col = n0 + wn * 64 + ni * 16 + row16;
    float bv = bias1[col] + (MODE == 0 ? bias2[col] : 0.0f);
#pragma unroll
    for (int mi = 0; mi < 4; ++mi) {
      int rbase = r0 + wm * 64 + mi * 16 + g4 * 4;
#pragma unroll
      for (int i = 0; i < 4; ++i)
        C[(size_t)(rbase + i) * 768 + col] = acc[mi][ni][i] + bv;
    }
  }
}

// Persistent recurrence kernel (R5): 24 blocks = 4 batch-groups x 6
// col-blocks, 512 threads (8 waves x 16 cols = 128 cols/block).
// Protocol = R3's proven data-as-flag (all shared traffic sc1 via IF;
// producer 8B atomic stores with zero-sentinel; consumer polls until both
// 8B halves of each 16B chunk are nonzero).  NEW: the 16x768 h-slab is
// polled cooperatively ONCE per block (3 coalesced chunks/thread) into a
// double-buffered XOR-swizzled LDS tile, then all 8 waves read MFMA
// fragments from LDS.  Cuts IF poll traffic 4.6MB -> 576KB per step and
// makes it linear instead of scattered.
__global__ __launch_bounds__(512) void scan_kernel(
    const float* __restrict__ W_hh, const float* __restrict__ xp,
    unsigned short* __restrict__ hseq) {
  __shared__ unsigned short hs[2][16 * 768];  // 2 x 24KB, XOR-swizzled rows
  const int tid = threadIdx.x;
  const int l = tid & 63;
  const int w = tid >> 6;              // wave 0..7
  const int bg = blockIdx.x / CB;      // batch group 0..3
  const int cb = blockIdx.x % CB;      // col block 0..5
  const int b0 = bg * 16;
  const int c0 = cb * 128;
  const int row16 = l & 15;
  const int g4 = l >> 4;

  // pack W_hh fragments: A[row=l&15 (out col)][k = kb*32 + (l>>4)*8 + j]
  uint4 wfrag[24];
  {
    const float* wr = W_hh + (size_t)(c0 + w * 16 + row16) * 768;
#pragma unroll
    for (int kb = 0; kb < 24; ++kb) {
      int k0 = kb * 32 + g4 * 8;
      float4 v0 = *(const float4*)(wr + k0);
      float4 v1 = *(const float4*)(wr + k0 + 4);
      uint4 p;
      p.x = f2b(v0.x) | ((unsigned)f2b(v0.y) << 16);
      p.y = f2b(v0.z) | ((unsigned)f2b(v0.w) << 16);
      p.z = f2b(v1.x) | ((unsigned)f2b(v1.y) << 16);
      p.w = f2b(v1.z) | ((unsigned)f2b(v1.w) << 16);
      wfrag[kb] = p;
    }
  }

  // cooperative-poll chunk geometry: 1536 16B chunks = 512 threads x 3
  // chunk ch = tid + 512*j: row = ch/96, col8 = ch%96 (8 bf16 per chunk)
  size_t goff[3];
  int loff[3];
#pragma unroll
  for (int j = 0; j < 3; ++j) {
    int ch = tid + 512 * j;
    int row = ch / 96;
    int col8 = ch - row * 96;
    goff[j] = (size_t)(b0 + row) * 768 + col8 * 8;
    loff[j] = row * 1536 + ((col8 * 16) ^ ((row & 7) << 4));
  }

  const size_t hcol = c0 + w * 16 + g4 * 4;
  unsigned short* hout_base = hseq + (size_t)(b0 + row16) * 768 + hcol;
  const float* xp_base = xp + (size_t)(b0 + row16) * 1024 * 768 + hcol;
  const int rdbase = row16 * 1536;
  const int rdswz = (row16 & 7) << 4;

  for (int t = 0; t < S_; ++t) {
    char* lbase = (char*)hs + (t & 1) * (16 * 768 * 2);
    float4 xpv = *(const float4*)(xp_base + (size_t)t * 768);  // off crit path
    const unsigned short* hin = hseq + (size_t)t * (B_ * H_);
    uint4 cv[3];
    if (t == 0) {
      // h0 (= zeros) pre-written by conv kernel; dispatch boundary
      // guarantees visibility; legitimately zero so no poll.
#pragma unroll
      for (int j = 0; j < 3; ++j)
        asm volatile("global_load_dwordx4 %0, %1, off sc1"
                     : "=&v"(cv[j])
                     : "v"(hin + goff[j]));
      asm volatile("s_waitcnt vmcnt(0)" ::: "memory");
      __builtin_amdgcn_sched_barrier(0);
    } else {
      unsigned done = 0;
      while (done != 7u) {
#pragma unroll
        for (int j = 0; j < 3; ++j)
          if (!(done & (1u << j)))
            asm volatile("global_load_dwordx4 %0, %1, off sc1"
                         : "=&v"(cv[j])
                         : "v"(hin + goff[j]));
        asm volatile("s_waitcnt vmcnt(0)" ::: "memory");
        __builtin_amdgcn_sched_barrier(0);  // keep checks after the waitcnt
#pragma unroll
        for (int j = 0; j < 3; ++j)
          if (!(done & (1u << j)) && (cv[j].x | cv[j].y) != 0 &&
              (cv[j].z | cv[j].w) != 0)
            done |= 1u << j;
      }
    }
    // stage slab into swizzled LDS, one barrier, then fragment reads
#pragma unroll
    for (int j = 0; j < 3; ++j) *(uint4*)(lbase + loff[j]) = cv[j];
    __syncthreads();

    uint4 hb[24];
#pragma unroll
    for (int kb = 0; kb < 24; ++kb)
      hb[kb] = *(const uint4*)(lbase + rdbase + ((kb * 64 + g4 * 16) ^ rdswz));

    f32x4 acc0 = {xpv.x, xpv.y, xpv.z, xpv.w};
    f32x4 acc1 = {0.f, 0.f, 0.f, 0.f};
    f32x4 acc2 = {0.f, 0.f, 0.f, 0.f};
    f32x4 acc3 = {0.f, 0.f, 0.f, 0.f};
#pragma unroll
    for (int kb = 0; kb < 24; kb += 4) {
      acc0 = __builtin_amdgcn_mfma_f32_16x16x32_bf16(
          __builtin_bit_cast(s16x8, wfrag[kb]),
          __builtin_bit_cast(s16x8, hb[kb]), acc0, 0, 0, 0);
      acc1 = __builtin_amdgcn_mfma_f32_16x16x32_bf16(
          __builtin_bit_cast(s16x8, wfrag[kb + 1]),
          __builtin_bit_cast(s16x8, hb[kb + 1]), acc1, 0, 0, 0);
      acc2 = __builtin_amdgcn_mfma_f32_16x16x32_bf16(
          __builtin_bit_cast(s16x8, wfrag[kb + 2]),
          __builtin_bit_cast(s16x8, hb[kb + 2]), acc2, 0, 0, 0);
      acc3 = __builtin_amdgcn_mfma_f32_16x16x32_bf16(
          __builtin_bit_cast(s16x8, wfrag[kb + 3]),
          __builtin_bit_cast(s16x8, hb[kb + 3]), acc3, 0, 0, 0);
    }
    f32x4 g = (acc0 + acc1) + (acc2 + acc3);
    float t0 = fast_tanh(g[0]), t1 = fast_tanh(g[1]);
    float t2 = fast_tanh(g[2]), t3 = fast_tanh(g[3]);
    unsigned long long pk = (unsigned long long)f2b(t0)
        | ((unsigned long long)f2b(t1) << 16)
        | ((unsigned long long)f2b(t2) << 32)
        | ((unsigned long long)f2b(t3) << 48);
    if (pk == 0) pk = 1;  // readiness sentinel: never store an all-zero word
    __hip_atomic_store(
        (unsigned long long*)(hout_base + (size_t)(t + 1) * (B_ * H_)), pk,
        __ATOMIC_RELAXED, __HIP_MEMORY_SCOPE_AGENT);
    // no trailing barrier needed: LDS is double-buffered, and a wave cannot
    // re-enter buffer (t&1) before all siblings finished reading it (its
    // step-t+1 poll transitively requires their step-t stores).
  }
}

extern "C" void kernel_launch(void* const* d_in, const int* in_sizes, int n_in,
                              void* d_out, int out_size, void* d_ws,
                              size_t ws_size, hipStream_t stream) {
  const float* hidden = (const float*)d_in[0];
  const float* x = (const float*)d_in[1];
  const float* W_ih = (const float*)d_in[2];
  const float* W_hh = (const float*)d_in[3];
  const float* b_ih = (const float*)d_in[4];
  const float* b_hh = (const float*)d_in[5];
  const float* W_fc = (const float*)d_in[6];
  const float* b_fc = (const float*)d_in[7];
  float* out = (float*)d_out;
  float* xp = out;  // xp [B*S][768] fp32 reuses the logits region (overwritten later)

  char* ws = (char*)d_ws;
  unsigned short* hseq = (unsigned short*)ws;  // [(S+1)][B][H] bf16
  size_t hseq_elems = (size_t)(S_ + 1) * B_ * H_;
  unsigned short* wih_b = hseq + hseq_elems;
  unsigned short* wfc_b = wih_b + 768 * 768;

  // zero h[1..S]: required every launch (data-as-flag poll; ws is not
  // re-poisoned between replays)
  hipMemsetAsync(hseq + (size_t)B_ * H_, 0, (size_t)S_ * B_ * H_ * 2, stream);
  conv_f2b_kernel<<<576, 256, 0, stream>>>(W_ih, wih_b, 768 * 768);
  conv_f2b_kernel<<<576, 256, 0, stream>>>(W_fc, wfc_b, 768 * 768);
  conv_f2b_kernel<<<48, 256, 0, stream>>>(hidden, hseq, B_ * H_);
  dim3 grid(512, 6);
  gemm_kernel<0><<<grid, 256, 0, stream>>>(x, wih_b, xp, b_ih, b_hh);
  scan_kernel<<<GB * CB, 512, 0, stream>>>(W_hh, xp, hseq);
  gemm_kernel<1><<<grid, 256, 0, stream>>>(hseq, wfc_b, out, b_fc, nullptr);
  tail_kernel<<<192, 256, 0, stream>>>(hseq + (size_t)S_ * B_ * H_,
                                       out + (size_t)65536 * 768, B_ * H_);
}

// Round 7
// 2900.690 us; speedup vs baseline: 4.2470x; 1.6881x over previous
//
#include <hip/hip_runtime.h>

#define B_ 64
#define S_ 1024
#define H_ 768
#define GB 4    // batch groups (16 rows each)
#define CB 6    // col-blocks per group (128 cols each)

typedef short s16x8 __attribute__((ext_vector_type(8)));
typedef float f32x4 __attribute__((ext_vector_type(4)));
typedef unsigned u32x4 __attribute__((ext_vector_type(4)));

__device__ __forceinline__ unsigned short f2b(float f) {
  unsigned u = __builtin_bit_cast(unsigned, f);
  u += 0x7FFFu + ((u >> 16) & 1u);
  return (unsigned short)(u >> 16);
}
__device__ __forceinline__ float b2f(unsigned short h) {
  unsigned u = ((unsigned)h) << 16;
  return __builtin_bit_cast(float, u);
}

// tanh(x) = 1 - 2/(1+e^{2x}); exact at +-inf, ~1e-7 rel err, no branches.
__device__ __forceinline__ float fast_tanh(float x) {
  float e = __builtin_amdgcn_exp2f(x * 2.8853900817779268f);  // e^{2x}
  return 1.0f - 2.0f * __builtin_amdgcn_rcpf(1.0f + e);
}

__global__ void conv_f2b_kernel(const float* __restrict__ src,
                                unsigned short* __restrict__ dst, int n) {
  int i = (blockIdx.x * blockDim.x + threadIdx.x) * 4;
  if (i >= n) return;
  float4 v = *(const float4*)(src + i);
  unsigned long long p = (unsigned long long)f2b(v.x)
      | ((unsigned long long)f2b(v.y) << 16)
      | ((unsigned long long)f2b(v.z) << 32)
      | ((unsigned long long)f2b(v.w) << 48);
  *(unsigned long long*)(dst + i) = p;
}

__global__ void tail_kernel(const unsigned short* __restrict__ src,
                            float* __restrict__ dst, int n) {
  int i = blockIdx.x * blockDim.x + threadIdx.x;
  if (i < n) dst[i] = b2f(src[i]);
}

// C[r][n] = sum_k A[r][k] * W[n][k] + bias.  MODE0: A fp32 (x), bias1+bias2.
// MODE1: A bf16 (hseq, row-gathered: r=b*1024+s -> hseq[(s+1)*64+b]), bias1.
template <int MODE>
__global__ __launch_bounds__(256) void gemm_kernel(
    const void* __restrict__ Aptr, const unsigned short* __restrict__ Bw,
    float* __restrict__ C, const float* __restrict__ bias1,
    const float* __restrict__ bias2) {
  __shared__ unsigned short As[128 * 64];
  __shared__ unsigned short Bs[128 * 64];
  const int tid = threadIdx.x;
  const int l = tid & 63;
  const int w = tid >> 6;
  const int wm = w >> 1, wn = w & 1;
  const int r0 = blockIdx.x * 128;
  const int n0 = blockIdx.y * 128;
  const int row16 = l & 15;
  const int g4 = l >> 4;
  const int swz = (l & 7) << 3;

  const int srow = tid >> 1;
  const int shalf = (tid & 1) * 32;
  size_t a_off;
  if (MODE == 0) {
    a_off = (size_t)(r0 + srow) * 768;
  } else {
    int ar = r0 + srow;
    a_off = ((size_t)((ar & 1023) + 1) * 64 + (ar >> 10)) * 768;
  }
  const size_t b_off = (size_t)(n0 + srow) * 768;
  const int swrow = (srow & 7) << 3;

  f32x4 acc[4][4] = {};

  for (int k0 = 0; k0 < 768; k0 += 64) {
    if (MODE == 0) {
      const float* Af = (const float*)Aptr + a_off + k0 + shalf;
#pragma unroll
      for (int jj = 0; jj < 4; ++jj) {
        float4 v0 = *(const float4*)(Af + jj * 8);
        float4 v1 = *(const float4*)(Af + jj * 8 + 4);
        uint4 p;
        p.x = f2b(v0.x) | ((unsigned)f2b(v0.y) << 16);
        p.y = f2b(v0.z) | ((unsigned)f2b(v0.w) << 16);
        p.z = f2b(v1.x) | ((unsigned)f2b(v1.y) << 16);
        p.w = f2b(v1.z) | ((unsigned)f2b(v1.w) << 16);
        int c = (shalf + jj * 8) ^ swrow;
        *(uint4*)(As + srow * 64 + c) = p;
      }
    } else {
      const unsigned short* Ab = (const unsigned short*)Aptr + a_off + k0 + shalf;
#pragma unroll
      for (int jj = 0; jj < 4; ++jj) {
        uint4 p = *(const uint4*)(Ab + jj * 8);
        int c = (shalf + jj * 8) ^ swrow;
        *(uint4*)(As + srow * 64 + c) = p;
      }
    }
    {
      const unsigned short* Bb = Bw + b_off + k0 + shalf;
#pragma unroll
      for (int jj = 0; jj < 4; ++jj) {
        uint4 p = *(const uint4*)(Bb + jj * 8);
        int c = (shalf + jj * 8) ^ swrow;
        *(uint4*)(Bs + srow * 64 + c) = p;
      }
    }
    __syncthreads();
#pragma unroll
    for (int kb = 0; kb < 2; ++kb) {
      int ccol = (kb * 32 + g4 * 8) ^ swz;
      s16x8 af[4], bfr[4];
#pragma unroll
      for (int mi = 0; mi < 4; ++mi)
        af[mi] = __builtin_bit_cast(
            s16x8, *(const uint4*)(As + (wm * 64 + mi * 16 + row16) * 64 + ccol));
#pragma unroll
      for (int ni = 0; ni < 4; ++ni)
        bfr[ni] = __builtin_bit_cast(
            s16x8, *(const uint4*)(Bs + (wn * 64 + ni * 16 + row16) * 64 + ccol));
#pragma unroll
      for (int mi = 0; mi < 4; ++mi)
#pragma unroll
        for (int ni = 0; ni < 4; ++ni)
          acc[mi][ni] = __builtin_amdgcn_mfma_f32_16x16x32_bf16(
              af[mi], bfr[ni], acc[mi][ni], 0, 0, 0);
    }
    __syncthreads();
  }
#pragma unroll
  for (int ni = 0; ni < 4; ++ni) {
    int col = n0 + wn * 64 + ni * 16 + row16;
    float bv = bias1[col] + (MODE == 0 ? bias2[col] : 0.0f);
#pragma unroll
    for (int mi = 0; mi < 4; ++mi) {
      int rbase = r0 + wm * 64 + mi * 16 + g4 * 4;
#pragma unroll
      for (int i = 0; i < 4; ++i)
        C[(size_t)(rbase + i) * 768 + col] = acc[mi][ni][i] + bv;
    }
  }
}

// Persistent recurrence (R6/R7): 24 blocks = 4 batch-groups x 6 col-blocks,
// 512 threads (8 waves x 16 cols).  Protocol = R3/R5's proven data-as-flag
// (sc1 via IF, zero-sentinel, memset-zeroed slab).  Deltas vs R5:
//  - own 128 cols are SELF-STAGED into the next LDS buffer and excluded
//    from the poll (1280 foreign chunks, single-writer LDS regions)
//  - outputs stored as paired 16B dwordx4 (lane l + l^16 via shfl):
//    halves the IF write-op count on the visibility path
//  - 4-bit XOR swizzle on LDS rows (read conflict 8-way -> <=4-way)
__global__ __launch_bounds__(512) void scan_kernel(
    const float* __restrict__ W_hh, const float* __restrict__ xp,
    unsigned short* __restrict__ hseq) {
  __shared__ unsigned short hs[2][16 * 768];  // 2 x 24KB
  const int tid = threadIdx.x;
  const int l = tid & 63;
  const int w = tid >> 6;
  const int bg = blockIdx.x / CB;
  const int cb = blockIdx.x % CB;
  const int b0 = bg * 16;
  const int c0 = cb * 128;
  const int row16 = l & 15;
  const int g4 = l >> 4;

  // pack W_hh fragments: A[row=l&15 (out col)][k = kb*32 + (l>>4)*8 + j]
  uint4 wfrag[24];
  {
    const float* wr = W_hh + (size_t)(c0 + w * 16 + row16) * 768;
#pragma unroll
    for (int kb = 0; kb < 24; ++kb) {
      int k0 = kb * 32 + g4 * 8;
      float4 v0 = *(const float4*)(wr + k0);
      float4 v1 = *(const float4*)(wr + k0 + 4);
      uint4 p;
      p.x = f2b(v0.x) | ((unsigned)f2b(v0.y) << 16);
      p.y = f2b(v0.z) | ((unsigned)f2b(v0.w) << 16);
      p.z = f2b(v1.x) | ((unsigned)f2b(v1.y) << 16);
      p.w = f2b(v1.z) | ((unsigned)f2b(v1.w) << 16);
      wfrag[kb] = p;
    }
  }

  // foreign-chunk geometry (t>=1): 80 foreign 16B chunks per row (own 16
  // excluded).  1280 = 512x2 + 256: threads <256 take a 3rd chunk.
  const int c08 = cb * 16;
  const int nch = (tid < 256) ? 3 : 2;
  size_t gF[3];
  int lF[3];
#pragma unroll
  for (int j = 0; j < 3; ++j) {
    int fi = (j < 2) ? (tid + 512 * j) : (1024 + (tid & 255));
    int row = fi / 80;
    int f = fi - row * 80;
    int col8 = f + (f >= c08 ? 16 : 0);
    gF[j] = (size_t)(b0 + row) * 768 + col8 * 8;
    lF[j] = row * 1536 + ((col8 * 16) ^ ((row & 15) << 4));
  }

  const size_t hcol = c0 + w * 16 + g4 * 4;
  unsigned short* hout_base = hseq + (size_t)(b0 + row16) * 768 + hcol;
  const float* xp_base = xp + (size_t)(b0 + row16) * 1024 * 768 + hcol;
  const int soff = row16 * 1536 + (((int)hcol * 2) ^ ((row16 & 15) << 4));
  const int rswz = (row16 & 15) << 4;

  for (int t = 0; t < S_; ++t) {
    char* lb = (char*)hs[t & 1];
    float4 xpv = *(const float4*)(xp_base + (size_t)t * 768);  // off crit path
    const unsigned short* hin = hseq + (size_t)t * (B_ * H_);
    if (t == 0) {
      // h0 (= zeros) pre-written by conv kernel; full slab incl. own cols.
      uint4 cv0[3];
#pragma unroll
      for (int j = 0; j < 3; ++j) {
        int ch = tid + 512 * j;
        int row = ch / 96;
        int col8 = ch - row * 96;
        asm volatile("global_load_dwordx4 %0, %1, off sc1"
                     : "=&v"(cv0[j])
                     : "v"(hin + (size_t)(b0 + row) * 768 + col8 * 8));
      }
      asm volatile("s_waitcnt vmcnt(0)" ::: "memory");
      __builtin_amdgcn_sched_barrier(0);
#pragma unroll
      for (int j = 0; j < 3; ++j) {
        int ch = tid + 512 * j;
        int row = ch / 96;
        int col8 = ch - row * 96;
        *(uint4*)(lb + row * 1536 + ((col8 * 16) ^ ((row & 15) << 4))) = cv0[j];
      }
    } else {
      uint4 cv[3];
      unsigned done = 0;
      const unsigned full = (nch == 3) ? 7u : 3u;
      while (done != full) {
        if (!(done & 1))
          asm volatile("global_load_dwordx4 %0, %1, off sc1"
                       : "=&v"(cv[0]) : "v"(hin + gF[0]));
        if (!(done & 2))
          asm volatile("global_load_dwordx4 %0, %1, off sc1"
                       : "=&v"(cv[1]) : "v"(hin + gF[1]));
        if (nch == 3 && !(done & 4))
          asm volatile("global_load_dwordx4 %0, %1, off sc1"
                       : "=&v"(cv[2]) : "v"(hin + gF[2]));
        asm volatile("s_waitcnt vmcnt(0)" ::: "memory");
        __builtin_amdgcn_sched_barrier(0);  // keep checks after the waitcnt
        if (!(done & 1) && (cv[0].x | cv[0].y) != 0 && (cv[0].z | cv[0].w) != 0) {
          done |= 1;
          *(uint4*)(lb + lF[0]) = cv[0];
        }
        if (!(done & 2) && (cv[1].x | cv[1].y) != 0 && (cv[1].z | cv[1].w) != 0) {
          done |= 2;
          *(uint4*)(lb + lF[1]) = cv[1];
        }
        if (nch == 3 && !(done & 4) && (cv[2].x | cv[2].y) != 0 &&
            (cv[2].z | cv[2].w) != 0) {
          done |= 4;
          *(uint4*)(lb + lF[2]) = cv[2];
        }
      }
    }
    __syncthreads();

    uint4 hb[24];
    const char* rb = lb + row16 * 1536;
#pragma unroll
    for (int kb = 0; kb < 24; ++kb)
      hb[kb] = *(const uint4*)(rb + ((kb * 64 + g4 * 16) ^ rswz));

    f32x4 acc0 = {xpv.x, xpv.y, xpv.z, xpv.w};
    f32x4 acc1 = {0.f, 0.f, 0.f, 0.f};
    f32x4 acc2 = {0.f, 0.f, 0.f, 0.f};
    f32x4 acc3 = {0.f, 0.f, 0.f, 0.f};
#pragma unroll
    for (int kb = 0; kb < 24; kb += 4) {
      acc0 = __builtin_amdgcn_mfma_f32_16x16x32_bf16(
          __builtin_bit_cast(s16x8, wfrag[kb]),
          __builtin_bit_cast(s16x8, hb[kb]), acc0, 0, 0, 0);
      acc1 = __builtin_amdgcn_mfma_f32_16x16x32_bf16(
          __builtin_bit_cast(s16x8, wfrag[kb + 1]),
          __builtin_bit_cast(s16x8, hb[kb + 1]), acc1, 0, 0, 0);
      acc2 = __builtin_amdgcn_mfma_f32_16x16x32_bf16(
          __builtin_bit_cast(s16x8, wfrag[kb + 2]),
          __builtin_bit_cast(s16x8, hb[kb + 2]), acc2, 0, 0, 0);
      acc3 = __builtin_amdgcn_mfma_f32_16x16x32_bf16(
          __builtin_bit_cast(s16x8, wfrag[kb + 3]),
          __builtin_bit_cast(s16x8, hb[kb + 3]), acc3, 0, 0, 0);
    }
    f32x4 g = (acc0 + acc1) + (acc2 + acc3);
    float t0 = fast_tanh(g[0]), t1 = fast_tanh(g[1]);
    float t2 = fast_tanh(g[2]), t3 = fast_tanh(g[3]);
    unsigned long long pk = (unsigned long long)f2b(t0)
        | ((unsigned long long)f2b(t1) << 16)
        | ((unsigned long long)f2b(t2) << 32)
        | ((unsigned long long)f2b(t3) << 48);
    if (pk == 0) pk = 1;  // readiness sentinel: never store an all-zero word

    // self-stage own cols for step t+1 (single writer of this LDS region)
    *(unsigned long long*)((char*)hs[(t + 1) & 1] + soff) = pk;

    // paired 16B global store: lane pairs (l, l^16) -> even-g4 lane stores 8 cols
    unsigned long long po = __shfl(pk, l ^ 16);
    if ((g4 & 1) == 0) {
      u32x4 st;
      st[0] = (unsigned)pk;
      st[1] = (unsigned)(pk >> 32);
      st[2] = (unsigned)po;
      st[3] = (unsigned)(po >> 32);
      asm volatile("global_store_dwordx4 %0, %1, off sc1" ::"v"(
                       hout_base + (size_t)(t + 1) * (B_ * H_)),
                   "v"(st)
                   : "memory");
    }
    // no trailing barrier: double-buffered LDS; a wave cannot reach step t+2
    // staging before all siblings' step-t reads are done (its t+2 poll
    // transitively requires every sibling's t+1 global store).
  }
}

extern "C" void kernel_launch(void* const* d_in, const int* in_sizes, int n_in,
                              void* d_out, int out_size, void* d_ws,
                              size_t ws_size, hipStream_t stream) {
  const float* hidden = (const float*)d_in[0];
  const float* x = (const float*)d_in[1];
  const float* W_ih = (const float*)d_in[2];
  const float* W_hh = (const float*)d_in[3];
  const float* b_ih = (const float*)d_in[4];
  const float* b_hh = (const float*)d_in[5];
  const float* W_fc = (const float*)d_in[6];
  const float* b_fc = (const float*)d_in[7];
  float* out = (float*)d_out;
  float* xp = out;  // xp [B*S][768] fp32 reuses the logits region (overwritten later)

  char* ws = (char*)d_ws;
  unsigned short* hseq = (unsigned short*)ws;  // [(S+1)][B][H] bf16
  size_t hseq_elems = (size_t)(S_ + 1) * B_ * H_;
  unsigned short* wih_b = hseq + hseq_elems;
  unsigned short* wfc_b = wih_b + 768 * 768;

  // zero h[1..S]: required every launch (data-as-flag poll; ws is not
  // re-poisoned between replays)
  (void)hipMemsetAsync(hseq + (size_t)B_ * H_, 0, (size_t)S_ * B_ * H_ * 2,
                       stream);
  conv_f2b_kernel<<<576, 256, 0, stream>>>(W_ih, wih_b, 768 * 768);
  conv_f2b_kernel<<<576, 256, 0, stream>>>(W_fc, wfc_b, 768 * 768);
  conv_f2b_kernel<<<48, 256, 0, stream>>>(hidden, hseq, B_ * H_);
  dim3 grid(512, 6);
  gemm_kernel<0><<<grid, 256, 0, stream>>>(x, wih_b, xp, b_ih, b_hh);
  scan_kernel<<<GB * CB, 512, 0, stream>>>(W_hh, xp, hseq);
  gemm_kernel<1><<<grid, 256, 0, stream>>>(hseq, wfc_b, out, b_fc, nullptr);
  tail_kernel<<<192, 256, 0, stream>>>(hseq + (size_t)S_ * B_ * H_,
                                       out + (size_t)65536 * 768, B_ * H_);
}